// Round 13
// baseline (320.817 us; speedup 1.0000x reference)
//
#include <hip/hip_runtime.h>

#define VOCAB 512
#define EMB   128
#define HID   64
#define BATCH 256
#define TLEN  1024
#define CH    16              // steps per chunk (16: poll overhead halved, I-cache safe)
#define NCH   (TLEN / CH)     // 64 chunks
#define RS    64              // ring depth in steps
#define RCH   (RS / CH)       // 4 chunks per ring
#define RW    80              // swizzled row width (floats): seg kg at 20*kg

typedef float v2f __attribute__((ext_vector_type(2)));

__device__ __forceinline__ float fast_tanh(float x) {
    // tanh(x) = 1 - 2/(exp(2x)+1); exact at both saturated ends.
    float e = __expf(2.0f * x);
    return 1.0f - 2.0f / (e + 1.0f);
}
__device__ __forceinline__ void lds_fence() {
    asm volatile("s_waitcnt lgkmcnt(0)" ::: "memory");
}
__device__ __forceinline__ void compiler_fence() {
    asm volatile("" ::: "memory");
}
__device__ __forceinline__ void nap() { __builtin_amdgcn_s_sleep(1); }

// Sum across the 4 lanes of a quad via DPP quad_perm adds (R13-proven).
__device__ __forceinline__ float quad_sum(float x) {
    int t1 = __builtin_amdgcn_update_dpp(0, __float_as_int(x), 0xB1, 0xF, 0xF, false);
    float s = x + __int_as_float(t1);
    int t2 = __builtin_amdgcn_update_dpp(0, __float_as_int(s), 0x4E, 0xF, 0xF, false);
    return s + __int_as_float(t2);
}

// 4-lane cooperative 64-dot (R12/R13-proven): lane (o=lane>>2, kg=lane&3)
// holds rows {o+16r} x cols [16kg,16kg+16) and a 16-float h segment.
// Returns the full dot for row o+16*kg.
__device__ __forceinline__ float dot_seg(const float4 s[4], const v2f w[4][8],
                                         int kg) {
    float z0, z1, z2, z3;
    #pragma unroll
    for (int r = 0; r < 4; ++r) {
        v2f a0 = v2f{0.f, 0.f}, a1 = v2f{0.f, 0.f};
        #pragma unroll
        for (int c = 0; c < 4; ++c) {
            float4 u = s[c];
            a0 = __builtin_elementwise_fma(v2f{u.x, u.y}, w[r][2 * c],     a0);
            a1 = __builtin_elementwise_fma(v2f{u.z, u.w}, w[r][2 * c + 1], a1);
        }
        float zr = quad_sum((a0.x + a0.y) + (a1.x + a1.y));
        if (r == 0) z0 = zr; else if (r == 1) z1 = zr;
        else if (r == 2) z2 = zr; else z3 = zr;
    }
    return (kg & 1) ? ((kg & 2) ? z3 : z1) : ((kg & 2) ? z2 : z0);
}

__device__ __forceinline__ void load_w(v2f w[4][8], const float* __restrict__ W,
                                       int o, int kg) {
    #pragma unroll
    for (int r = 0; r < 4; ++r) {
        const float4* wr = (const float4*)(W + (o + 16 * r) * HID + 16 * kg);
        #pragma unroll
        for (int c = 0; c < 4; ++c) {
            float4 u = wr[c];
            w[r][2 * c]     = v2f{u.x, u.y};
            w[r][2 * c + 1] = v2f{u.z, u.w};
        }
    }
}

// Load this lane's 16-float segment (4x ds_read_b128, R13-proven layout;
// RW=80 skew puts the 4 kg-addresses in disjoint bank quads).
__device__ __forceinline__ void seg_load(float4 s[4], const float* rowkg) {
    const float4* p = (const float4*)rowkg;
    #pragma unroll
    for (int c = 0; c < 4; ++c) s[c] = p[c];
}

// ---------------------------------------------------------------------------
// Kernel 1: P0[v][i] = sum_e emb[v][e]*Wih0[i][e] + bih0[i] + bhh0[i]  (fp32)
// ---------------------------------------------------------------------------
__global__ void __launch_bounds__(64) p0_kernel(
    const float* __restrict__ emb,
    const float* __restrict__ wih0,
    const float* __restrict__ bih0,
    const float* __restrict__ bhh0,
    float* __restrict__ P0)
{
    const int v = blockIdx.x;
    const int i = threadIdx.x;
    const float4* er = (const float4*)(emb  + v * EMB);
    const float4* wr = (const float4*)(wih0 + i * EMB);
    float a0 = 0.f, a1 = 0.f, a2 = 0.f, a3 = 0.f;
    #pragma unroll
    for (int k = 0; k < EMB / 4; ++k) {
        float4 e4 = er[k];
        float4 w4 = wr[k];
        a0 = fmaf(e4.x, w4.x, a0);
        a1 = fmaf(e4.y, w4.y, a1);
        a2 = fmaf(e4.z, w4.z, a2);
        a3 = fmaf(e4.w, w4.w, a3);
    }
    P0[v * HID + i] = (a0 + a1) + (a2 + a3) + bih0[i] + bhh0[i];
}

// ---------------------------------------------------------------------------
// Kernel 2 (R20): R19 (226us best) + batched b128 a/p paths.
// R19 post-mortem: ~200 cyc/step of the remaining 531 is DS-pipe occupancy
// (23 DS instrs/step across 4 clients). a/p traffic is chunk-granular ->
// transpose those rings to [slot][row][CH]: 16 b32 scatters become 4 b128
// per path per chunk (4x fewer instrs, 2x byte-rate). DS ops/step 23 -> ~14.
//   wave0 : h0[t] = tanh(a[t] + Whh0 h0[t-1])       (prio1, a: 4 b128/chunk)
//   wave1 : p1[t] = b1 + Wih1 h0[t]                 (prio0, p buffered in regs)
//   wave2 : h1[t] = tanh(p1[t] + Whh1 h1[t-1])      (prio1) + MLP head
//   wave3 : feeder a[t][row] = P0[x[t]][row]        (prio0, 4 b128/chunk)
// ---------------------------------------------------------------------------
__global__ void __launch_bounds__(256, 1) rnn_kernel(
    const int*   __restrict__ xs,
    const float* __restrict__ P0,
    const float* __restrict__ Whh0,
    const float* __restrict__ Wih1,
    const float* __restrict__ Whh1,
    const float* __restrict__ bih1,
    const float* __restrict__ bhh1,
    const float* __restrict__ W1,
    const float* __restrict__ b1,
    const float* __restrict__ W2,
    const float* __restrict__ b2,
    float*       __restrict__ out)
{
    __shared__ float a_ring[RCH][HID][CH];  // 16 KiB; [slot][row][i], b128 IO
    __shared__ float h0ring[RS][RW];        // 20 KiB, swizzled rows
    __shared__ float p1ring[RCH][HID][CH];  // 16 KiB; [slot][row][i], b128 IO
    __shared__ float h1buf[2][RW];          // swizzled
    __shared__ int   flags[4];

    const int b    = blockIdx.x;
    const int tid  = threadIdx.x;
    const int wv   = tid >> 6;
    const int lane = tid & 63;
    const int o    = lane >> 2;         // output group (0..15)
    const int kg   = lane & 3;          // k-segment   (0..3)
    const int row  = o + 16 * kg;       // output row this lane owns
    const int wrs  = 20 * kg + o;       // swizzled write slot for `row`

    const int* xrow = xs + b * TLEN;
    // vz == 0, but opaque to uniformity analysis -> forces VECTOR loads
    // (vmcnt path) for the x reads instead of s_load (lgkmcnt path).
    const int vz = (int)__builtin_amdgcn_mbcnt_lo(0u, 0u);

    if (tid < 4) flags[tid] = 0;
    __syncthreads();                     // the ONLY barrier in the kernel

    volatile int* vf = (volatile int*)flags;

    if (wv == 0) {
        // ================= wave0: layer-0 recurrence (slim, prio1) ========
        v2f w0[4][8];
        load_w(w0, Whh0, o, kg);
        __builtin_amdgcn_s_setprio(1);

        float4 s0[4];                    // h0[t-1] segment (regs)
        #pragma unroll
        for (int c = 0; c < 4; ++c) s0[c] = float4{0.f, 0.f, 0.f, 0.f};

        #pragma unroll 1
        for (int k = 0; k < NCH; ++k) {
            while (vf[3] < k + 1) nap(); // feeder: a_ring chunk k ready
            if (k >= RCH) {              // h0ring slot-reuse guard (wave1)
                while (vf[1] < k - (RCH - 1)) nap();
            }
            compiler_fence();
            const int slot = k & (RCH - 1);
            const int base = slot * CH;
            float a8[CH];                // bulk a reads: 4 ds_read_b128
            #pragma unroll
            for (int q = 0; q < CH / 4; ++q) {
                float4 t4 = *(const float4*)&a_ring[slot][row][4 * q];
                a8[4 * q + 0] = t4.x; a8[4 * q + 1] = t4.y;
                a8[4 * q + 2] = t4.z; a8[4 * q + 3] = t4.w;
            }
            #pragma unroll
            for (int i = 0; i < CH; ++i) {
                float z  = dot_seg(s0, w0, kg) + a8[i];
                float hv = fast_tanh(z);
                h0ring[base + i][wrs] = hv;               // 1 ds_write_b32
                seg_load(s0, &h0ring[base + i][20 * kg]); // readback, 4 b128
            }
            lds_fence();
            if (lane == 0) vf[0] = k + 1;
        }
    } else if (wv == 1) {
        // ================= wave1: p1 projection (no recurrence, prio0) ====
        v2f wp[4][8];
        load_w(wp, Wih1, o, kg);
        const float b1s = bih1[row] + bhh1[row];

        #pragma unroll 1
        for (int k = 0; k < NCH; ++k) {
            while (vf[0] < k + 1) nap();
            if (k >= RCH) { while (vf[2] < k - (RCH - 1)) nap(); }
            compiler_fence();
            const int slot = k & (RCH - 1);
            const int base = slot * CH;
            float pbuf[CH];              // p values buffered in regs
            float4 c0[4];
            seg_load(c0, &h0ring[base][20 * kg]);
            #pragma unroll
            for (int i = 0; i < CH; ++i) {
                float4 nx[4];
                if (i < CH - 1) seg_load(nx, &h0ring[base + i + 1][20 * kg]);
                pbuf[i] = dot_seg(c0, wp, kg) + b1s;
                if (i < CH - 1) {
                    #pragma unroll
                    for (int c = 0; c < 4; ++c) c0[c] = nx[c];
                }
            }
            #pragma unroll
            for (int q = 0; q < CH / 4; ++q)   // batched write: 4 ds_write_b128
                *(float4*)&p1ring[slot][row][4 * q] =
                    float4{pbuf[4 * q], pbuf[4 * q + 1],
                           pbuf[4 * q + 2], pbuf[4 * q + 3]};
            lds_fence();
            if (lane == 0) vf[1] = k + 1;
        }
    } else if (wv == 2) {
        // ================= wave2: layer-1 recurrence + MLP (prio1) ========
        v2f w2[4][8];
        load_w(w2, Whh1, o, kg);
        __builtin_amdgcn_s_setprio(1);

        float4 s1[4];
        #pragma unroll
        for (int c = 0; c < 4; ++c) s1[c] = float4{0.f, 0.f, 0.f, 0.f};

        #pragma unroll 1
        for (int k = 0; k < NCH; ++k) {
            while (vf[1] < k + 1) nap();
            compiler_fence();
            const int slot = k & (RCH - 1);
            float p[CH];                 // bulk p reads: 4 ds_read_b128
            #pragma unroll
            for (int q = 0; q < CH / 4; ++q) {
                float4 t4 = *(const float4*)&p1ring[slot][row][4 * q];
                p[4 * q + 0] = t4.x; p[4 * q + 1] = t4.y;
                p[4 * q + 2] = t4.z; p[4 * q + 3] = t4.w;
            }
            #pragma unroll
            for (int i = 0; i < CH; ++i) {
                const int t = k * CH + i;
                float z  = dot_seg(s1, w2, kg) + p[i];
                float hv = fast_tanh(z);
                h1buf[t & 1][wrs] = hv;                   // 1 ds_write_b32
                seg_load(s1, &h1buf[t & 1][20 * kg]);     // readback, 4 b128
            }
            lds_fence();                 // p reads consumed, h1 writes done
            if (lane == 0) vf[2] = k + 1;
        }
        __builtin_amdgcn_s_setprio(0);
        // ---- MLP head: y = relu(h1 @ W1^T + b1) @ W2^T + b2 ----
        float r = 0.f;
        if (lane < 32) {
            float acc = b1[lane];
            const float* w1row = W1 + lane * HID;
            const float* hN    = h1buf[(TLEN - 1) & 1];
            #pragma unroll
            for (int j = 0; j < HID; ++j)
                acc = fmaf(w1row[j], hN[20 * (j >> 4) + (j & 15)], acc);
            r = fmaxf(acc, 0.f) * W2[lane];
        }
        #pragma unroll
        for (int off = 32; off > 0; off >>= 1) r += __shfl_down(r, off);
        if (lane == 0) out[b] = r + b2[0];
    } else {
        // ================= wave3: feeder (x loads + P0 gather, prio0) =====
        #pragma unroll 1
        for (int k = 0; k < NCH; ++k) {
            if (k >= RCH) {              // a_ring slot-reuse guard (wave0)
                while (vf[0] < k - (RCH - 1)) nap();
                compiler_fence();
            }
            const int* xp = xrow + k * CH;
            int xv[CH];
            #pragma unroll
            for (int i = 0; i < CH; ++i)
                xv[i] = xp[i + vz] & (VOCAB - 1);
            float av[CH];
            #pragma unroll
            for (int i = 0; i < CH; ++i)
                av[i] = P0[xv[i] * HID + row];
            const int slot = k & (RCH - 1);
            #pragma unroll
            for (int q = 0; q < CH / 4; ++q)   // batched write: 4 ds_write_b128
                *(float4*)&a_ring[slot][row][4 * q] =
                    float4{av[4 * q], av[4 * q + 1],
                           av[4 * q + 2], av[4 * q + 3]};
            lds_fence();                 // a_ring writes visible
            if (lane == 0) vf[3] = k + 1;
        }
    }
}

extern "C" void kernel_launch(void* const* d_in, const int* in_sizes, int n_in,
                              void* d_out, int out_size, void* d_ws, size_t ws_size,
                              hipStream_t stream)
{
    const int*   x    = (const int*)d_in[0];
    const float* emb  = (const float*)d_in[1];
    const float* Wih0 = (const float*)d_in[2];
    const float* Whh0 = (const float*)d_in[3];
    const float* bih0 = (const float*)d_in[4];
    const float* bhh0 = (const float*)d_in[5];
    const float* Wih1 = (const float*)d_in[6];
    const float* Whh1 = (const float*)d_in[7];
    const float* bih1 = (const float*)d_in[8];
    const float* bhh1 = (const float*)d_in[9];
    const float* W1   = (const float*)d_in[10];
    const float* b1   = (const float*)d_in[11];
    const float* W2   = (const float*)d_in[12];
    const float* b2   = (const float*)d_in[13];

    float* P0 = (float*)d_ws;   // 512*64*4 = 128 KiB scratch

    hipLaunchKernelGGL(p0_kernel, dim3(VOCAB), dim3(HID), 0, stream,
                       emb, Wih0, bih0, bhh0, P0);
    hipLaunchKernelGGL(rnn_kernel, dim3(BATCH), dim3(256), 0, stream,
                       x, P0, Whh0, Wih1, Whh1, bih1, bhh1,
                       W1, b1, W2, b2, (float*)d_out);
}

// Round 14
// 284.531 us; speedup vs baseline: 1.1275x; 1.1275x over previous
//
#include <hip/hip_runtime.h>

#define VOCAB 512
#define EMB   128
#define HID   64
#define BATCH 256
#define TLEN  1024
#define CH    16              // steps per chunk (16: poll overhead halved, I-cache safe)
#define NCH   (TLEN / CH)     // 64 chunks
#define RS    64              // ring depth in steps
#define RCH   (RS / CH)       // 4 chunks per ring
#define RW    80              // swizzled row width (floats): seg kg at 20*kg

typedef float v2f __attribute__((ext_vector_type(2)));

__device__ __forceinline__ float fast_tanh(float x) {
    // tanh(x) = 1 - 2/(exp(2x)+1); exact at both saturated ends.
    float e = __expf(2.0f * x);
    return 1.0f - 2.0f / (e + 1.0f);
}
__device__ __forceinline__ void lds_fence() {
    asm volatile("s_waitcnt lgkmcnt(0)" ::: "memory");
}
__device__ __forceinline__ void compiler_fence() {
    asm volatile("" ::: "memory");
}
__device__ __forceinline__ void nap() { __builtin_amdgcn_s_sleep(1); }

__device__ __forceinline__ float dpp_xor1(float x) {    // quad_perm [1,0,3,2]
    return __int_as_float(__builtin_amdgcn_update_dpp(
        0, __float_as_int(x), 0xB1, 0xF, 0xF, false));
}
__device__ __forceinline__ float dpp_xor2(float x) {    // quad_perm [2,3,0,1]
    return __int_as_float(__builtin_amdgcn_update_dpp(
        0, __float_as_int(x), 0x4E, 0xF, 0xF, false));
}

// 4-lane cooperative 64-dot with REDUCE-SCATTER finish (R21).
// Lane (o=lane>>2, kg=lane&3) holds rows {o+16r} x cols [16kg,16kg+16).
// R19's quad_sum computed all 4 row-sums in every lane (16 instr) then
// selected one (3 instr); the 2-stage butterfly reduce-scatter below gives
// each lane ITS row's full sum directly (12 instr, same addition tree ->
// bitwise-identical result).
__device__ __forceinline__ float dot_seg_rs(const float4 s[4],
                                            const v2f w[4][8],
                                            bool b0, bool b1m) {
    float p[4];
    #pragma unroll
    for (int r = 0; r < 4; ++r) {
        v2f a0 = v2f{0.f, 0.f}, a1 = v2f{0.f, 0.f};
        #pragma unroll
        for (int c = 0; c < 4; ++c) {
            float4 u = s[c];
            a0 = __builtin_elementwise_fma(v2f{u.x, u.y}, w[r][2 * c],     a0);
            a1 = __builtin_elementwise_fma(v2f{u.z, u.w}, w[r][2 * c + 1], a1);
        }
        v2f t = a0 + a1;
        p[r] = t.x + t.y;
    }
    // stage 1 (partner ^1): keep row (kg&1) of pair {0,1} and of pair {2,3}
    float x01 = b0 ? p[1] : p[0];
    float y01 = b0 ? p[0] : p[1];          // the value the partner needs
    x01 += dpp_xor1(y01);
    float x23 = b0 ? p[3] : p[2];
    float y23 = b0 ? p[2] : p[3];
    x23 += dpp_xor1(y23);
    // stage 2 (partner ^2): keep the (kg&2)-selected half
    float u = b1m ? x23 : x01;
    float v = b1m ? x01 : x23;
    return u + dpp_xor2(v);                // full sum of row o+16*kg
}

__device__ __forceinline__ void load_w(v2f w[4][8], const float* __restrict__ W,
                                       int o, int kg) {
    #pragma unroll
    for (int r = 0; r < 4; ++r) {
        const float4* wr = (const float4*)(W + (o + 16 * r) * HID + 16 * kg);
        #pragma unroll
        for (int c = 0; c < 4; ++c) {
            float4 u = wr[c];
            w[r][2 * c]     = v2f{u.x, u.y};
            w[r][2 * c + 1] = v2f{u.z, u.w};
        }
    }
}

// Load this lane's 16-float segment (4x ds_read_b128, R13-proven layout;
// RW=80 skew puts the 4 kg-addresses in disjoint bank quads).
__device__ __forceinline__ void seg_load(float4 s[4], const float* rowkg) {
    const float4* p = (const float4*)rowkg;
    #pragma unroll
    for (int c = 0; c < 4; ++c) s[c] = p[c];
}

// ---------------------------------------------------------------------------
// Kernel 1: P0[v][i] = sum_e emb[v][e]*Wih0[i][e] + bih0[i] + bhh0[i]  (fp32)
// ---------------------------------------------------------------------------
__global__ void __launch_bounds__(64) p0_kernel(
    const float* __restrict__ emb,
    const float* __restrict__ wih0,
    const float* __restrict__ bih0,
    const float* __restrict__ bhh0,
    float* __restrict__ P0)
{
    const int v = blockIdx.x;
    const int i = threadIdx.x;
    const float4* er = (const float4*)(emb  + v * EMB);
    const float4* wr = (const float4*)(wih0 + i * EMB);
    float a0 = 0.f, a1 = 0.f, a2 = 0.f, a3 = 0.f;
    #pragma unroll
    for (int k = 0; k < EMB / 4; ++k) {
        float4 e4 = er[k];
        float4 w4 = wr[k];
        a0 = fmaf(e4.x, w4.x, a0);
        a1 = fmaf(e4.y, w4.y, a1);
        a2 = fmaf(e4.z, w4.z, a2);
        a3 = fmaf(e4.w, w4.w, a3);
    }
    P0[v * HID + i] = (a0 + a1) + (a2 + a3) + bih0[i] + bhh0[i];
}

// ---------------------------------------------------------------------------
// Kernel 2 (R21): R19's proven 4-wave topology (226us best) with the
// reduce-scatter dot. R20 lesson locked in: 16B-aligned transposed rings
// are >=8-way b128-conflicted on 32-bank LDS -> b32 bulk paths stay.
//   wave0 : h0[t] = tanh(a[t] + Whh0 h0[t-1])       (prio1, a_ring-fed)
//   wave1 : p1[t] = b1 + Wih1 h0[t]                 (prio0)
//   wave2 : h1[t] = tanh(p1[t] + Whh1 h1[t-1])      (prio1) + MLP head
//   wave3 : feeder a[t][row] = P0[x[t]][row]        (prio0, off-chain)
// ---------------------------------------------------------------------------
__global__ void __launch_bounds__(256, 1) rnn_kernel(
    const int*   __restrict__ xs,
    const float* __restrict__ P0,
    const float* __restrict__ Whh0,
    const float* __restrict__ Wih1,
    const float* __restrict__ Whh1,
    const float* __restrict__ bih1,
    const float* __restrict__ bhh1,
    const float* __restrict__ W1,
    const float* __restrict__ b1,
    const float* __restrict__ W2,
    const float* __restrict__ b2,
    float*       __restrict__ out)
{
    __shared__ float a_ring[RS][HID];   // 16 KiB; [t][row] = P0[x[t]][row]
    __shared__ float h0ring[RS][RW];    // 20 KiB, swizzled rows
    __shared__ float p1ring[RS][HID];   // 16 KiB, plain rows
    __shared__ float h1buf[2][RW];      // swizzled
    __shared__ int   flags[4];

    const int b    = blockIdx.x;
    const int tid  = threadIdx.x;
    const int wv   = tid >> 6;
    const int lane = tid & 63;
    const int o    = lane >> 2;         // output group (0..15)
    const int kg   = lane & 3;          // k-segment   (0..3)
    const int row  = o + 16 * kg;       // output row this lane owns
    const int wrs  = 20 * kg + o;       // swizzled write slot for `row`
    const bool b0  = (kg & 1) != 0;     // reduce-scatter keep/send selects
    const bool b1m = (kg & 2) != 0;

    const int* xrow = xs + b * TLEN;
    // vz == 0, but opaque to uniformity analysis -> forces VECTOR loads
    // (vmcnt path) for the x reads instead of s_load (lgkmcnt path).
    const int vz = (int)__builtin_amdgcn_mbcnt_lo(0u, 0u);

    if (tid < 4) flags[tid] = 0;
    __syncthreads();                     // the ONLY barrier in the kernel

    volatile int* vf = (volatile int*)flags;

    if (wv == 0) {
        // ================= wave0: layer-0 recurrence (slim, prio1) ========
        v2f w0[4][8];
        load_w(w0, Whh0, o, kg);
        __builtin_amdgcn_s_setprio(1);

        float4 s0[4];                    // h0[t-1] segment (regs)
        #pragma unroll
        for (int c = 0; c < 4; ++c) s0[c] = float4{0.f, 0.f, 0.f, 0.f};

        #pragma unroll 1
        for (int k = 0; k < NCH; ++k) {
            while (vf[3] < k + 1) nap(); // feeder: a_ring chunk k ready
            if (k >= RCH) {              // h0ring slot-reuse guard (wave1)
                while (vf[1] < k - (RCH - 1)) nap();
            }
            compiler_fence();
            const int base = (k & (RCH - 1)) * CH;
            float a8[CH];                // bulk a reads (b32, 2-way = free)
            #pragma unroll
            for (int i = 0; i < CH; ++i) a8[i] = a_ring[base + i][row];
            #pragma unroll
            for (int i = 0; i < CH; ++i) {
                float z  = dot_seg_rs(s0, w0, b0, b1m) + a8[i];
                float hv = fast_tanh(z);
                h0ring[base + i][wrs] = hv;               // 1 ds_write_b32
                seg_load(s0, &h0ring[base + i][20 * kg]); // readback, 4 b128
            }
            lds_fence();
            if (lane == 0) vf[0] = k + 1;
        }
    } else if (wv == 1) {
        // ================= wave1: p1 projection (no recurrence, prio0) ====
        v2f wp[4][8];
        load_w(wp, Wih1, o, kg);
        const float b1s = bih1[row] + bhh1[row];

        #pragma unroll 1
        for (int k = 0; k < NCH; ++k) {
            while (vf[0] < k + 1) nap();
            if (k >= RCH) { while (vf[2] < k - (RCH - 1)) nap(); }
            compiler_fence();
            const int base = (k & (RCH - 1)) * CH;
            float4 c0[4];
            seg_load(c0, &h0ring[base][20 * kg]);
            #pragma unroll
            for (int i = 0; i < CH; ++i) {
                float4 nx[4];
                if (i < CH - 1) seg_load(nx, &h0ring[base + i + 1][20 * kg]);
                float pv = dot_seg_rs(c0, wp, b0, b1m) + b1s;
                p1ring[base + i][row] = pv;
                if (i < CH - 1) {
                    #pragma unroll
                    for (int c = 0; c < 4; ++c) c0[c] = nx[c];
                }
            }
            lds_fence();
            if (lane == 0) vf[1] = k + 1;
        }
    } else if (wv == 2) {
        // ================= wave2: layer-1 recurrence + MLP (prio1) ========
        v2f w2[4][8];
        load_w(w2, Whh1, o, kg);
        __builtin_amdgcn_s_setprio(1);

        float4 s1[4];
        #pragma unroll
        for (int c = 0; c < 4; ++c) s1[c] = float4{0.f, 0.f, 0.f, 0.f};

        #pragma unroll 1
        for (int k = 0; k < NCH; ++k) {
            while (vf[1] < k + 1) nap();
            compiler_fence();
            const int base = (k & (RCH - 1)) * CH;
            float p[CH];                 // bulk p prefetch (b32, 2-way free)
            #pragma unroll
            for (int i = 0; i < CH; ++i) p[i] = p1ring[base + i][row];
            #pragma unroll
            for (int i = 0; i < CH; ++i) {
                const int t = k * CH + i;
                float z  = dot_seg_rs(s1, w2, b0, b1m) + p[i];
                float hv = fast_tanh(z);
                h1buf[t & 1][wrs] = hv;                   // 1 ds_write_b32
                seg_load(s1, &h1buf[t & 1][20 * kg]);     // readback, 4 b128
            }
            lds_fence();                 // p reads consumed, h1 writes done
            if (lane == 0) vf[2] = k + 1;
        }
        __builtin_amdgcn_s_setprio(0);
        // ---- MLP head: y = relu(h1 @ W1^T + b1) @ W2^T + b2 ----
        float r = 0.f;
        if (lane < 32) {
            float acc = b1[lane];
            const float* w1row = W1 + lane * HID;
            const float* hN    = h1buf[(TLEN - 1) & 1];
            #pragma unroll
            for (int j = 0; j < HID; ++j)
                acc = fmaf(w1row[j], hN[20 * (j >> 4) + (j & 15)], acc);
            r = fmaxf(acc, 0.f) * W2[lane];
        }
        #pragma unroll
        for (int off = 32; off > 0; off >>= 1) r += __shfl_down(r, off);
        if (lane == 0) out[b] = r + b2[0];
    } else {
        // ================= wave3: feeder (x loads + P0 gather, prio0) =====
        #pragma unroll 1
        for (int k = 0; k < NCH; ++k) {
            if (k >= RCH) {              // a_ring slot-reuse guard (wave0)
                while (vf[0] < k - (RCH - 1)) nap();
                compiler_fence();
            }
            const int* xp = xrow + k * CH;
            int xv[CH];
            #pragma unroll
            for (int i = 0; i < CH; ++i)
                xv[i] = xp[i + vz] & (VOCAB - 1);
            float av[CH];
            #pragma unroll
            for (int i = 0; i < CH; ++i)
                av[i] = P0[xv[i] * HID + row];
            const int base = (k & (RCH - 1)) * CH;
            #pragma unroll
            for (int i = 0; i < CH; ++i)
                a_ring[base + i][row] = av[i];
            lds_fence();                 // a_ring writes visible
            if (lane == 0) vf[3] = k + 1;
        }
    }
}

extern "C" void kernel_launch(void* const* d_in, const int* in_sizes, int n_in,
                              void* d_out, int out_size, void* d_ws, size_t ws_size,
                              hipStream_t stream)
{
    const int*   x    = (const int*)d_in[0];
    const float* emb  = (const float*)d_in[1];
    const float* Wih0 = (const float*)d_in[2];
    const float* Whh0 = (const float*)d_in[3];
    const float* bih0 = (const float*)d_in[4];
    const float* bhh0 = (const float*)d_in[5];
    const float* Wih1 = (const float*)d_in[6];
    const float* Whh1 = (const float*)d_in[7];
    const float* bih1 = (const float*)d_in[8];
    const float* bhh1 = (const float*)d_in[9];
    const float* W1   = (const float*)d_in[10];
    const float* b1   = (const float*)d_in[11];
    const float* W2   = (const float*)d_in[12];
    const float* b2   = (const float*)d_in[13];

    float* P0 = (float*)d_ws;   // 512*64*4 = 128 KiB scratch

    hipLaunchKernelGGL(p0_kernel, dim3(VOCAB), dim3(HID), 0, stream,
                       emb, Wih0, bih0, bhh0, P0);
    hipLaunchKernelGGL(rnn_kernel, dim3(BATCH), dim3(256), 0, stream,
                       x, P0, Whh0, Wih1, Whh1, bih1, bhh1,
                       W1, b1, W2, b2, (float*)d_out);
}